// Round 10
// baseline (218.640 us; speedup 1.0000x reference)
//
#include <hip/hip_runtime.h>
#include <cstdint>

#define ZFULL 136
#define NCTX 16
#define KCLS 75

typedef __bf16 bf16x8 __attribute__((ext_vector_type(8)));
typedef float f32x4 __attribute__((ext_vector_type(4)));

__device__ __forceinline__ ushort bf16_rne(float v) {
  uint32_t u = __float_as_uint(v);
  return (ushort)((u + 0x7fffu + ((u >> 16) & 1u)) >> 16);
}

__device__ __forceinline__ float rdlane(float v, int l) {
  return __int_as_float(__builtin_amdgcn_readlane(__float_as_int(v), l));
}

// ---- pack A: [CH/16 m_tiles][5 k_tiles][2 h][64 lane][8 j] ushorts (bf16) ----
__global__ __launch_bounds__(256) void pack_A(const float* __restrict__ z,
                                              const int* __restrict__ labels,
                                              ushort* __restrict__ Apk,
                                              int b0, int CH) {
  int idx = blockIdx.x * 256 + threadIdx.x;  // (mt,kt,h,lane)
  int lane = idx & 63;
  int h = (idx >> 6) & 1;
  int kt = (idx >> 7) % 5;
  int mt = idx / 640;
  if (mt >= CH / 16) return;
  int m = b0 + mt * 16 + (lane & 15);
  int kbase = kt * 32 + (lane >> 4) * 8;
  ushort o[8];
#pragma unroll
  for (int j = 0; j < 8; ++j) {
    int k = kbase + j;
    float v = 0.0f;
    if (k < ZFULL) v = z[(size_t)m * ZFULL + k];
    else if (k < ZFULL + NCTX) v = (float)labels[(size_t)m * NCTX + (k - ZFULL)];
    ushort hi = bf16_rne(v);
    if (h == 0) o[j] = hi;
    else {
      float fhi = __uint_as_float((uint32_t)hi << 16);
      o[j] = bf16_rne(v - fhi);
    }
  }
  uint4 w;
  w.x = (uint32_t)o[0] | ((uint32_t)o[1] << 16);
  w.y = (uint32_t)o[2] | ((uint32_t)o[3] << 16);
  w.z = (uint32_t)o[4] | ((uint32_t)o[5] << 16);
  w.w = (uint32_t)o[6] | ((uint32_t)o[7] << 16);
  *(uint4*)(Apk + (size_t)idx * 8) = w;
}

// ---- pack B: [256 n_tiles][5 k_tiles][2 h][64 lane][8 j] ushorts (bf16) ----
__global__ __launch_bounds__(256) void pack_B(const float* __restrict__ Kp,
                                              const float* __restrict__ Lm,
                                              ushort* __restrict__ Bpk) {
  int idx = blockIdx.x * 256 + threadIdx.x;
  int lane = idx & 63;
  int h = (idx >> 6) & 1;
  int kt = (idx >> 7) % 5;
  int nt = idx / 640;
  if (nt >= 256) return;
  int n = nt * 16 + (lane & 15);
  int kbase = kt * 32 + (lane >> 4) * 8;
  ushort o[8];
#pragma unroll
  for (int j = 0; j < 8; ++j) {
    int k = kbase + j;
    float v = 0.0f;
    if (k < ZFULL) v = Kp[(size_t)n * ZFULL + k];
    else if (k < ZFULL + NCTX) v = Lm[(size_t)n * NCTX + (k - ZFULL)];
    ushort hi = bf16_rne(v);
    if (h == 0) o[j] = hi;
    else {
      float fhi = __uint_as_float((uint32_t)hi << 16);
      o[j] = bf16_rne(v - fhi);
    }
  }
  uint4 w;
  w.x = (uint32_t)o[0] | ((uint32_t)o[1] << 16);
  w.y = (uint32_t)o[2] | ((uint32_t)o[3] << 16);
  w.z = (uint32_t)o[4] | ((uint32_t)o[5] << 16);
  w.w = (uint32_t)o[6] | ((uint32_t)o[7] << 16);
  *(uint4*)(Bpk + (size_t)idx * 8) = w;
}

// ---- split-bf16 MFMA GEMM, 128x128 block tile, no LDS (L2-resident packed operands) ----
__global__ __launch_bounds__(256) void gemm_mfma(const ushort* __restrict__ Apk,
                                                 const ushort* __restrict__ Bpk,
                                                 const float* __restrict__ base_log,
                                                 float* __restrict__ rates) {
  const int tid = threadIdx.x;
  const int lane = tid & 63;
  const int w = tid >> 6;
  const int wm = w & 1, wn = w >> 1;
  const int m_tile0 = blockIdx.x * 8 + wm * 4;
  const int n_tile0 = blockIdx.y * 8 + wn * 4;

  f32x4 acc[4][4] = {};

#pragma unroll
  for (int kt = 0; kt < 5; ++kt) {
    bf16x8 ah[4], al[4], bh[4], bl[4];
#pragma unroll
    for (int mt = 0; mt < 4; ++mt) {
      size_t off = (((size_t)(m_tile0 + mt) * 5 + kt) * 128 + lane) * 8;
      ah[mt] = *(const bf16x8*)(Apk + off);
      al[mt] = *(const bf16x8*)(Apk + off + 512);
    }
#pragma unroll
    for (int nt = 0; nt < 4; ++nt) {
      size_t off = (((size_t)(n_tile0 + nt) * 5 + kt) * 128 + lane) * 8;
      bh[nt] = *(const bf16x8*)(Bpk + off);
      bl[nt] = *(const bf16x8*)(Bpk + off + 512);
    }
#pragma unroll
    for (int mt = 0; mt < 4; ++mt)
#pragma unroll
      for (int nt = 0; nt < 4; ++nt) {
        acc[mt][nt] = __builtin_amdgcn_mfma_f32_16x16x32_bf16(ah[mt], bh[nt], acc[mt][nt], 0, 0, 0);
        acc[mt][nt] = __builtin_amdgcn_mfma_f32_16x16x32_bf16(ah[mt], bl[nt], acc[mt][nt], 0, 0, 0);
        acc[mt][nt] = __builtin_amdgcn_mfma_f32_16x16x32_bf16(al[mt], bh[nt], acc[mt][nt], 0, 0, 0);
      }
  }

  const int col_l = lane & 15;
  const int row_l = (lane >> 4) * 4;
#pragma unroll
  for (int mt = 0; mt < 4; ++mt) {
#pragma unroll
    for (int nt = 0; nt < 4; ++nt) {
      int n = (n_tile0 + nt) * 16 + col_l;
      int i = n >> 6, j = n & 63;
      float bse = base_log[n];
#pragma unroll
      for (int r = 0; r < 4; ++r) {
        int m = (m_tile0 + mt) * 16 + row_l + r;
        float v = acc[mt][nt][r] + bse;
        v = fminf(fmaxf(v, -15.0f), 3.0f);
        float e = (i == j) ? 0.0f : expf(v);
        rates[(size_t)m * 4096 + n] = e;
      }
    }
  }
}

// ===== row-layout Gauss-Jordan with LDS pivot-row broadcast =====
// lane = row; row held as 16 f32x4 quads (static indices). Per step: lane K
// ds_write_b128's its trailing quads; explicit compiler memory fence +
// lgkmcnt(0) drain (round 9 NaN: per-thread semantics let the compiler hoist
// the broadcast loads above the exec-masked stores — a wave-level data race);
// then all lanes ds_read_b128 (uniform address -> broadcast) and fma.
template <int K>
struct GJ {
  static __device__ __forceinline__ void run(f32x4 (&A)[16], float& d, int lane,
                                             f32x4* pr) {
    constexpr int Q0 = K >> 2;
    constexpr int T0 = K & 3;
    if (lane == K) {
#pragma unroll
      for (int q = Q0; q < 16; ++q) pr[q] = A[q];
    }
    // fence: forbid hoisting the reads above the masked stores (compiler),
    // and drain the ds_write before any lane reads (hardware).
    asm volatile("s_waitcnt lgkmcnt(0)" ::: "memory");
    f32x4 P0 = pr[Q0];
    float piv = P0[T0];
    float rp = __builtin_amdgcn_rcpf(piv);
    bool isk = (lane == K);
    float m = isk ? 0.0f : A[Q0][T0] * rp;
    d = isk ? piv : d;
#pragma unroll
    for (int t = T0 + 1; t < 4; ++t) A[Q0][t] = fmaf(-m, P0[t], A[Q0][t]);
#pragma unroll
    for (int q = Q0 + 1; q < 16; ++q) {
      f32x4 P = pr[q];
#pragma unroll
      for (int t = 0; t < 4; ++t) A[q][t] = fmaf(-m, P[t], A[q][t]);
    }
    // WAR fence: next step's stores must not move above this step's reads.
    asm volatile("" ::: "memory");
    GJ<K + 1>::run(A, d, lane, pr);
  }
};
template <>
struct GJ<63> {
  static __device__ __forceinline__ void run(f32x4 (&)[16], float&, int, f32x4*) {}
};

// ---- solve + attention + logits: one wave per batch ----
__global__ __launch_bounds__(256) void solve_kernel(const float* __restrict__ rates,
                                                    const int* __restrict__ labels,
                                                    const float* __restrict__ Bm,
                                                    float* __restrict__ out,
                                                    int b0) {
  __shared__ float Blds[64][16];
  __shared__ float xbuf[4][64];
  __shared__ float att_lds[4][16];
  __shared__ float acc[4][80];
  __shared__ f32x4 prow[4][16];   // per-wave pivot-row broadcast buffer

  const int tid = threadIdx.x;
  for (int idx = tid; idx < 1024; idx += 256)
    Blds[idx >> 4][idx & 15] = Bm[idx];

  const int wave = tid >> 6;
  const int lane = tid & 63;
  const int batch = b0 + blockIdx.x * 4 + wave;
  const float* Rb = rates + (size_t)(blockIdx.x * 4 + wave) * 4096;

  // ---- pass 1: cs = colsum of column `lane` (diag entries are 0) ----
  float cs = 0.0f;
#pragma unroll
  for (int i = 0; i < 64; ++i) cs += Rb[i * 64 + lane];

  // ---- pass 2: lane holds ROW `lane` as 16 quads (L1/L2 hot) ----
  const float* R = Rb + (size_t)lane * 64;
  f32x4 A[16];
#pragma unroll
  for (int q = 0; q < 16; ++q) A[q] = *(const f32x4*)(R + q * 4);

  // ---- build K_mod: diag = -colsum (rows 0..62); row 63 = all ones ----
  const bool is63 = (lane == 63);
  const float ncs = -cs;
#pragma unroll
  for (int q = 0; q < 16; ++q)
#pragma unroll
    for (int t = 0; t < 4; ++t) {
      int j = q * 4 + t;
      float v = (lane == j) ? ncs : A[q][t];
      A[q][t] = is63 ? 1.0f : v;
    }

  // ---- Gauss-Jordan pivots 0..62 (no pivoting; col-diag-dominant). b=e63 untouched. ----
  float d = 1.0f;
  GJ<0>::run(A, d, lane, prow[wave]);

  // row i<63:  d_i*x_i + A[i][63]*x63 = 0 ;  row 63: A[63][63]*x63 = 1
  float m6363 = rdlane(A[15][3], 63);
  float x63 = 1.0f / m6363;
  float x = is63 ? x63 : -A[15][3] * x63 * __builtin_amdgcn_rcpf(d);

  // clip >= 0 and normalize
  x = fmaxf(x, 0.0f);
  float s = x;
  s += __shfl_xor(s, 32); s += __shfl_xor(s, 16); s += __shfl_xor(s, 8);
  s += __shfl_xor(s, 4);  s += __shfl_xor(s, 2);  s += __shfl_xor(s, 1);
  x = x / s;

  xbuf[wave][lane] = x;
  if (lane < 16) {
    acc[wave][lane] = 1e-10f;
    acc[wave][16 + lane] = 1e-10f;
    acc[wave][32 + lane] = 1e-10f;
    acc[wave][48 + lane] = 1e-10f;
    acc[wave][64 + lane] = 1e-10f;
  }
  __syncthreads();

  // q[t] = p . B[:,t] for t = lane < 16
  float q = 0.0f;
  if (lane < 16) {
#pragma unroll 8
    for (int n = 0; n < 64; ++n) q = fmaf(xbuf[wave][n], Blds[n][lane], q);
  }
  float qm = q;
  qm = fmaxf(qm, __shfl_xor(qm, 8)); qm = fmaxf(qm, __shfl_xor(qm, 4));
  qm = fmaxf(qm, __shfl_xor(qm, 2)); qm = fmaxf(qm, __shfl_xor(qm, 1));
  float e = expf(q - qm);
  float es = e;
  es += __shfl_xor(es, 8); es += __shfl_xor(es, 4);
  es += __shfl_xor(es, 2); es += __shfl_xor(es, 1);
  if (lane < 16) att_lds[wave][lane] = e / es;
  __syncthreads();

  // deterministic serial bucket-accumulate (no atomics)
  if (lane == 0) {
#pragma unroll
    for (int n = 0; n < 16; ++n) {
      int lb = labels[(size_t)batch * 16 + n];
      acc[wave][lb - 1] += att_lds[wave][n];
    }
  }
  __syncthreads();

  float* ob = out + (size_t)batch * 75;
  ob[lane] = logf(acc[wave][lane]);
  if (lane < 11) ob[64 + lane] = logf(acc[wave][64 + lane]);
}

extern "C" void kernel_launch(void* const* d_in, const int* in_sizes, int n_in,
                              void* d_out, int out_size, void* d_ws, size_t ws_size,
                              hipStream_t stream) {
  const float* z      = (const float*)d_in[0];
  const int*   labels = (const int*)d_in[1];
  const float* Kp     = (const float*)d_in[2];
  const float* Lm     = (const float*)d_in[3];
  const float* Bm     = (const float*)d_in[4];
  const float* base   = (const float*)d_in[5];
  float* out = (float*)d_out;

  const int bsz = in_sizes[0] / ZFULL;  // 8192

  const size_t B_bytes = (size_t)256 * 5 * 2 * 64 * 8 * sizeof(ushort);  // 2.62 MB
  int CH = bsz;
  while (CH > 128) {
    size_t A_bytes = (size_t)(CH / 16) * 5 * 2 * 64 * 8 * sizeof(ushort);
    size_t need = B_bytes + A_bytes + (size_t)CH * 4096 * sizeof(float);
    if (need <= ws_size) break;
    CH >>= 1;
  }
  ushort* Bpk = (ushort*)d_ws;
  ushort* Apk = (ushort*)((char*)d_ws + B_bytes);
  size_t A_bytes = (size_t)(CH / 16) * 5 * 2 * 64 * 8 * sizeof(ushort);
  float* rates = (float*)((char*)d_ws + B_bytes + A_bytes);

  pack_B<<<(256 * 640 + 255) / 256, 256, 0, stream>>>(Kp, Lm, Bpk);

  for (int b0 = 0; b0 < bsz; b0 += CH) {
    int a_threads = (CH / 16) * 640;
    pack_A<<<(a_threads + 255) / 256, 256, 0, stream>>>(z, labels, Apk, b0, CH);
    dim3 g(CH / 128, 32);
    gemm_mfma<<<g, 256, 0, stream>>>(Apk, Bpk, base, rates);
    solve_kernel<<<CH / 4, 256, 0, stream>>>(rates, labels, Bm, out, b0);
  }
}

// Round 11
// 143.648 us; speedup vs baseline: 1.5221x; 1.5221x over previous
//
#include <hip/hip_runtime.h>
#include <cstdint>

#define ZFULL 136
#define NCTX 16
#define KCLS 75

typedef __bf16 bf16x8 __attribute__((ext_vector_type(8)));
typedef float f32x4 __attribute__((ext_vector_type(4)));

__device__ __forceinline__ ushort bf16_rne(float v) {
  uint32_t u = __float_as_uint(v);
  return (ushort)((u + 0x7fffu + ((u >> 16) & 1u)) >> 16);
}

__device__ __forceinline__ float rdlane(float v, int l) {
  return __int_as_float(__builtin_amdgcn_readlane(__float_as_int(v), l));
}

// ---- pack A: [CH/16 m_tiles][5 k_tiles][2 h][64 lane][8 j] ushorts (bf16) ----
__global__ __launch_bounds__(256) void pack_A(const float* __restrict__ z,
                                              const int* __restrict__ labels,
                                              ushort* __restrict__ Apk,
                                              int b0, int CH) {
  int idx = blockIdx.x * 256 + threadIdx.x;  // (mt,kt,h,lane)
  int lane = idx & 63;
  int h = (idx >> 6) & 1;
  int kt = (idx >> 7) % 5;
  int mt = idx / 640;
  if (mt >= CH / 16) return;
  int m = b0 + mt * 16 + (lane & 15);
  int kbase = kt * 32 + (lane >> 4) * 8;
  ushort o[8];
#pragma unroll
  for (int j = 0; j < 8; ++j) {
    int k = kbase + j;
    float v = 0.0f;
    if (k < ZFULL) v = z[(size_t)m * ZFULL + k];
    else if (k < ZFULL + NCTX) v = (float)labels[(size_t)m * NCTX + (k - ZFULL)];
    ushort hi = bf16_rne(v);
    if (h == 0) o[j] = hi;
    else {
      float fhi = __uint_as_float((uint32_t)hi << 16);
      o[j] = bf16_rne(v - fhi);
    }
  }
  uint4 w;
  w.x = (uint32_t)o[0] | ((uint32_t)o[1] << 16);
  w.y = (uint32_t)o[2] | ((uint32_t)o[3] << 16);
  w.z = (uint32_t)o[4] | ((uint32_t)o[5] << 16);
  w.w = (uint32_t)o[6] | ((uint32_t)o[7] << 16);
  *(uint4*)(Apk + (size_t)idx * 8) = w;
}

// ---- pack B: [256 n_tiles][5 k_tiles][2 h][64 lane][8 j] ushorts (bf16) ----
__global__ __launch_bounds__(256) void pack_B(const float* __restrict__ Kp,
                                              const float* __restrict__ Lm,
                                              ushort* __restrict__ Bpk) {
  int idx = blockIdx.x * 256 + threadIdx.x;
  int lane = idx & 63;
  int h = (idx >> 6) & 1;
  int kt = (idx >> 7) % 5;
  int nt = idx / 640;
  if (nt >= 256) return;
  int n = nt * 16 + (lane & 15);
  int kbase = kt * 32 + (lane >> 4) * 8;
  ushort o[8];
#pragma unroll
  for (int j = 0; j < 8; ++j) {
    int k = kbase + j;
    float v = 0.0f;
    if (k < ZFULL) v = Kp[(size_t)n * ZFULL + k];
    else if (k < ZFULL + NCTX) v = Lm[(size_t)n * NCTX + (k - ZFULL)];
    ushort hi = bf16_rne(v);
    if (h == 0) o[j] = hi;
    else {
      float fhi = __uint_as_float((uint32_t)hi << 16);
      o[j] = bf16_rne(v - fhi);
    }
  }
  uint4 w;
  w.x = (uint32_t)o[0] | ((uint32_t)o[1] << 16);
  w.y = (uint32_t)o[2] | ((uint32_t)o[3] << 16);
  w.z = (uint32_t)o[4] | ((uint32_t)o[5] << 16);
  w.w = (uint32_t)o[6] | ((uint32_t)o[7] << 16);
  *(uint4*)(Bpk + (size_t)idx * 8) = w;
}

// ---- split-bf16 MFMA GEMM -> bf16 rates (halves the HBM round trip) ----
__global__ __launch_bounds__(256) void gemm_mfma(const ushort* __restrict__ Apk,
                                                 const ushort* __restrict__ Bpk,
                                                 const float* __restrict__ base_log,
                                                 ushort* __restrict__ rates) {
  const int tid = threadIdx.x;
  const int lane = tid & 63;
  const int w = tid >> 6;
  const int wm = w & 1, wn = w >> 1;
  const int m_tile0 = blockIdx.x * 8 + wm * 4;
  const int n_tile0 = blockIdx.y * 8 + wn * 4;

  f32x4 acc[4][4] = {};

#pragma unroll
  for (int kt = 0; kt < 5; ++kt) {
    bf16x8 ah[4], al[4], bh[4], bl[4];
#pragma unroll
    for (int mt = 0; mt < 4; ++mt) {
      size_t off = (((size_t)(m_tile0 + mt) * 5 + kt) * 128 + lane) * 8;
      ah[mt] = *(const bf16x8*)(Apk + off);
      al[mt] = *(const bf16x8*)(Apk + off + 512);
    }
#pragma unroll
    for (int nt = 0; nt < 4; ++nt) {
      size_t off = (((size_t)(n_tile0 + nt) * 5 + kt) * 128 + lane) * 8;
      bh[nt] = *(const bf16x8*)(Bpk + off);
      bl[nt] = *(const bf16x8*)(Bpk + off + 512);
    }
#pragma unroll
    for (int mt = 0; mt < 4; ++mt)
#pragma unroll
      for (int nt = 0; nt < 4; ++nt) {
        acc[mt][nt] = __builtin_amdgcn_mfma_f32_16x16x32_bf16(ah[mt], bh[nt], acc[mt][nt], 0, 0, 0);
        acc[mt][nt] = __builtin_amdgcn_mfma_f32_16x16x32_bf16(ah[mt], bl[nt], acc[mt][nt], 0, 0, 0);
        acc[mt][nt] = __builtin_amdgcn_mfma_f32_16x16x32_bf16(al[mt], bh[nt], acc[mt][nt], 0, 0, 0);
      }
  }

  const int col_l = lane & 15;
  const int row_l = (lane >> 4) * 4;
#pragma unroll
  for (int mt = 0; mt < 4; ++mt) {
#pragma unroll
    for (int nt = 0; nt < 4; ++nt) {
      int n = (n_tile0 + nt) * 16 + col_l;
      int i = n >> 6, j = n & 63;
      float bse = base_log[n];
#pragma unroll
      for (int r = 0; r < 4; ++r) {
        int m = (m_tile0 + mt) * 16 + row_l + r;
        float v = acc[mt][nt][r] + bse;
        v = fminf(fmaxf(v, -15.0f), 3.0f);
        ushort e = (i == j) ? (ushort)0 : bf16_rne(expf(v));
        rates[(size_t)m * 4096 + n] = e;
      }
    }
  }
}

// ===== row-layout Gauss-Jordan: lane = row, regs = columns (round-7 form) =====
template <int K>
struct GJ {
  static __device__ __forceinline__ void run(float (&a)[64], float& d, int lane) {
    float piv = rdlane(a[K], K);
    float rp = __builtin_amdgcn_rcpf(piv);
    bool isk = (lane == K);
    float m = isk ? 0.0f : a[K] * rp;
    d = isk ? piv : d;
#pragma unroll
    for (int j = K + 1; j < 64; ++j) {
      float p = rdlane(a[j], K);
      a[j] = fmaf(-m, p, a[j]);
    }
    GJ<K + 1>::run(a, d, lane);
  }
};
template <>
struct GJ<63> {
  static __device__ __forceinline__ void run(float (&)[64], float&, int) {}
};

// ---- solve + attention + logits: one wave per batch (bf16 rates input) ----
__global__ __launch_bounds__(256) void solve_kernel(const ushort* __restrict__ rates,
                                                    const int* __restrict__ labels,
                                                    const float* __restrict__ Bm,
                                                    float* __restrict__ out,
                                                    int b0) {
  __shared__ float Blds[64][16];
  __shared__ float xbuf[4][64];
  __shared__ float att_lds[4][16];
  __shared__ float acc[4][80];

  const int tid = threadIdx.x;
  for (int idx = tid; idx < 1024; idx += 256)
    Blds[idx >> 4][idx & 15] = Bm[idx];

  const int wave = tid >> 6;
  const int lane = tid & 63;
  const int batch = b0 + blockIdx.x * 4 + wave;
  const ushort* Rb = rates + (size_t)(blockIdx.x * 4 + wave) * 4096;

  // ---- pass 1: cs = colsum of column `lane` (diag entries are 0) ----
  float cs = 0.0f;
#pragma unroll
  for (int i = 0; i < 64; ++i)
    cs += __uint_as_float((uint32_t)Rb[i * 64 + lane] << 16);

  // ---- pass 2: lane holds ROW `lane`: a[j] = rates[lane][j] (L1/L2 hot) ----
  const ushort* R = Rb + (size_t)lane * 64;
  float a[64];
#pragma unroll
  for (int q = 0; q < 8; ++q) {
    uint4 u = *(const uint4*)(R + q * 8);
    uint32_t ww[4] = {u.x, u.y, u.z, u.w};
#pragma unroll
    for (int t = 0; t < 4; ++t) {
      a[q * 8 + t * 2 + 0] = __uint_as_float(ww[t] << 16);
      a[q * 8 + t * 2 + 1] = __uint_as_float(ww[t] & 0xFFFF0000u);
    }
  }

  // ---- build K_mod: diag = -colsum (rows 0..62); row 63 = all ones ----
  const bool is63 = (lane == 63);
  const float ncs = -cs;
#pragma unroll
  for (int j = 0; j < 64; ++j) {
    float v = (lane == j) ? ncs : a[j];
    a[j] = is63 ? 1.0f : v;
  }

  // ---- Gauss-Jordan pivots 0..62 (no pivoting; col-diag-dominant). b=e63 untouched. ----
  float d = 1.0f;
  GJ<0>::run(a, d, lane);

  // row i<63:  d_i*x_i + a[63]*x63 = 0 ;  row 63: a[63]*x63 = 1
  float m6363 = rdlane(a[63], 63);
  float x63 = 1.0f / m6363;
  float x = is63 ? x63 : -a[63] * x63 * __builtin_amdgcn_rcpf(d);

  // clip >= 0 and normalize
  x = fmaxf(x, 0.0f);
  float s = x;
  s += __shfl_xor(s, 32); s += __shfl_xor(s, 16); s += __shfl_xor(s, 8);
  s += __shfl_xor(s, 4);  s += __shfl_xor(s, 2);  s += __shfl_xor(s, 1);
  x = x / s;

  xbuf[wave][lane] = x;
  if (lane < 16) {
    acc[wave][lane] = 1e-10f;
    acc[wave][16 + lane] = 1e-10f;
    acc[wave][32 + lane] = 1e-10f;
    acc[wave][48 + lane] = 1e-10f;
    acc[wave][64 + lane] = 1e-10f;
  }
  __syncthreads();

  // q[t] = p . B[:,t] for t = lane < 16
  float q = 0.0f;
  if (lane < 16) {
#pragma unroll 8
    for (int n = 0; n < 64; ++n) q = fmaf(xbuf[wave][n], Blds[n][lane], q);
  }
  float qm = q;
  qm = fmaxf(qm, __shfl_xor(qm, 8)); qm = fmaxf(qm, __shfl_xor(qm, 4));
  qm = fmaxf(qm, __shfl_xor(qm, 2)); qm = fmaxf(qm, __shfl_xor(qm, 1));
  float e = expf(q - qm);
  float es = e;
  es += __shfl_xor(es, 8); es += __shfl_xor(es, 4);
  es += __shfl_xor(es, 2); es += __shfl_xor(es, 1);
  if (lane < 16) att_lds[wave][lane] = e / es;
  __syncthreads();

  // deterministic serial bucket-accumulate (no atomics)
  if (lane == 0) {
#pragma unroll
    for (int n = 0; n < 16; ++n) {
      int lb = labels[(size_t)batch * 16 + n];
      acc[wave][lb - 1] += att_lds[wave][n];
    }
  }
  __syncthreads();

  float* ob = out + (size_t)batch * 75;
  ob[lane] = logf(acc[wave][lane]);
  if (lane < 11) ob[64 + lane] = logf(acc[wave][64 + lane]);
}

extern "C" void kernel_launch(void* const* d_in, const int* in_sizes, int n_in,
                              void* d_out, int out_size, void* d_ws, size_t ws_size,
                              hipStream_t stream) {
  const float* z      = (const float*)d_in[0];
  const int*   labels = (const int*)d_in[1];
  const float* Kp     = (const float*)d_in[2];
  const float* Lm     = (const float*)d_in[3];
  const float* Bm     = (const float*)d_in[4];
  const float* base   = (const float*)d_in[5];
  float* out = (float*)d_out;

  const int bsz = in_sizes[0] / ZFULL;  // 8192

  const size_t B_bytes = (size_t)256 * 5 * 2 * 64 * 8 * sizeof(ushort);  // 2.62 MB
  int CH = bsz;
  while (CH > 128) {
    size_t A_bytes = (size_t)(CH / 16) * 5 * 2 * 64 * 8 * sizeof(ushort);
    size_t need = B_bytes + A_bytes + (size_t)CH * 4096 * sizeof(ushort);
    if (need <= ws_size) break;
    CH >>= 1;
  }
  ushort* Bpk = (ushort*)d_ws;
  ushort* Apk = (ushort*)((char*)d_ws + B_bytes);
  size_t A_bytes = (size_t)(CH / 16) * 5 * 2 * 64 * 8 * sizeof(ushort);
  ushort* rates = (ushort*)((char*)d_ws + B_bytes + A_bytes);

  pack_B<<<(256 * 640 + 255) / 256, 256, 0, stream>>>(Kp, Lm, Bpk);

  for (int b0 = 0; b0 < bsz; b0 += CH) {
    int a_threads = (CH / 16) * 640;
    pack_A<<<(a_threads + 255) / 256, 256, 0, stream>>>(z, labels, Apk, b0, CH);
    dim3 g(CH / 128, 32);
    gemm_mfma<<<g, 256, 0, stream>>>(Apk, Bpk, base, rates);
    solve_kernel<<<CH / 4, 256, 0, stream>>>(rates, labels, Bm, out, b0);
  }
}

// Round 12
// 142.695 us; speedup vs baseline: 1.5322x; 1.0067x over previous
//
#include <hip/hip_runtime.h>
#include <cstdint>

#define ZFULL 136
#define NCTX 16
#define KCLS 75

typedef __bf16 bf16x8 __attribute__((ext_vector_type(8)));
typedef float f32x4 __attribute__((ext_vector_type(4)));

__device__ __forceinline__ ushort bf16_rne(float v) {
  uint32_t u = __float_as_uint(v);
  return (ushort)((u + 0x7fffu + ((u >> 16) & 1u)) >> 16);
}

__device__ __forceinline__ float rdlane(float v, int l) {
  return __int_as_float(__builtin_amdgcn_readlane(__float_as_int(v), l));
}

// broadcast lane `srcLane`'s value to all lanes via the LDS pipe (ds_bpermute:
// uniform address -> HW broadcast, result in VGPR -> no SGPR hazard, and the
// LDS pipe overlaps the VALU pipe carrying the fmas).
__device__ __forceinline__ float bperm(float v, int srcLane) {
  return __int_as_float(__builtin_amdgcn_ds_bpermute(srcLane * 4, __float_as_int(v)));
}

// ---- pack A: [CH/16 m_tiles][5 k_tiles][2 h][64 lane][8 j] ushorts (bf16) ----
__global__ __launch_bounds__(256) void pack_A(const float* __restrict__ z,
                                              const int* __restrict__ labels,
                                              ushort* __restrict__ Apk,
                                              int b0, int CH) {
  int idx = blockIdx.x * 256 + threadIdx.x;  // (mt,kt,h,lane)
  int lane = idx & 63;
  int h = (idx >> 6) & 1;
  int kt = (idx >> 7) % 5;
  int mt = idx / 640;
  if (mt >= CH / 16) return;
  int m = b0 + mt * 16 + (lane & 15);
  int kbase = kt * 32 + (lane >> 4) * 8;
  ushort o[8];
#pragma unroll
  for (int j = 0; j < 8; ++j) {
    int k = kbase + j;
    float v = 0.0f;
    if (k < ZFULL) v = z[(size_t)m * ZFULL + k];
    else if (k < ZFULL + NCTX) v = (float)labels[(size_t)m * NCTX + (k - ZFULL)];
    ushort hi = bf16_rne(v);
    if (h == 0) o[j] = hi;
    else {
      float fhi = __uint_as_float((uint32_t)hi << 16);
      o[j] = bf16_rne(v - fhi);
    }
  }
  uint4 w;
  w.x = (uint32_t)o[0] | ((uint32_t)o[1] << 16);
  w.y = (uint32_t)o[2] | ((uint32_t)o[3] << 16);
  w.z = (uint32_t)o[4] | ((uint32_t)o[5] << 16);
  w.w = (uint32_t)o[6] | ((uint32_t)o[7] << 16);
  *(uint4*)(Apk + (size_t)idx * 8) = w;
}

// ---- pack B: [256 n_tiles][5 k_tiles][2 h][64 lane][8 j] ushorts (bf16) ----
__global__ __launch_bounds__(256) void pack_B(const float* __restrict__ Kp,
                                              const float* __restrict__ Lm,
                                              ushort* __restrict__ Bpk) {
  int idx = blockIdx.x * 256 + threadIdx.x;
  int lane = idx & 63;
  int h = (idx >> 6) & 1;
  int kt = (idx >> 7) % 5;
  int nt = idx / 640;
  if (nt >= 256) return;
  int n = nt * 16 + (lane & 15);
  int kbase = kt * 32 + (lane >> 4) * 8;
  ushort o[8];
#pragma unroll
  for (int j = 0; j < 8; ++j) {
    int k = kbase + j;
    float v = 0.0f;
    if (k < ZFULL) v = Kp[(size_t)n * ZFULL + k];
    else if (k < ZFULL + NCTX) v = Lm[(size_t)n * NCTX + (k - ZFULL)];
    ushort hi = bf16_rne(v);
    if (h == 0) o[j] = hi;
    else {
      float fhi = __uint_as_float((uint32_t)hi << 16);
      o[j] = bf16_rne(v - fhi);
    }
  }
  uint4 w;
  w.x = (uint32_t)o[0] | ((uint32_t)o[1] << 16);
  w.y = (uint32_t)o[2] | ((uint32_t)o[3] << 16);
  w.z = (uint32_t)o[4] | ((uint32_t)o[5] << 16);
  w.w = (uint32_t)o[6] | ((uint32_t)o[7] << 16);
  *(uint4*)(Bpk + (size_t)idx * 8) = w;
}

// ---- split-bf16 MFMA GEMM -> bf16 rates (halves the HBM round trip) ----
__global__ __launch_bounds__(256) void gemm_mfma(const ushort* __restrict__ Apk,
                                                 const ushort* __restrict__ Bpk,
                                                 const float* __restrict__ base_log,
                                                 ushort* __restrict__ rates) {
  const int tid = threadIdx.x;
  const int lane = tid & 63;
  const int w = tid >> 6;
  const int wm = w & 1, wn = w >> 1;
  const int m_tile0 = blockIdx.x * 8 + wm * 4;
  const int n_tile0 = blockIdx.y * 8 + wn * 4;

  f32x4 acc[4][4] = {};

#pragma unroll
  for (int kt = 0; kt < 5; ++kt) {
    bf16x8 ah[4], al[4], bh[4], bl[4];
#pragma unroll
    for (int mt = 0; mt < 4; ++mt) {
      size_t off = (((size_t)(m_tile0 + mt) * 5 + kt) * 128 + lane) * 8;
      ah[mt] = *(const bf16x8*)(Apk + off);
      al[mt] = *(const bf16x8*)(Apk + off + 512);
    }
#pragma unroll
    for (int nt = 0; nt < 4; ++nt) {
      size_t off = (((size_t)(n_tile0 + nt) * 5 + kt) * 128 + lane) * 8;
      bh[nt] = *(const bf16x8*)(Bpk + off);
      bl[nt] = *(const bf16x8*)(Bpk + off + 512);
    }
#pragma unroll
    for (int mt = 0; mt < 4; ++mt)
#pragma unroll
      for (int nt = 0; nt < 4; ++nt) {
        acc[mt][nt] = __builtin_amdgcn_mfma_f32_16x16x32_bf16(ah[mt], bh[nt], acc[mt][nt], 0, 0, 0);
        acc[mt][nt] = __builtin_amdgcn_mfma_f32_16x16x32_bf16(ah[mt], bl[nt], acc[mt][nt], 0, 0, 0);
        acc[mt][nt] = __builtin_amdgcn_mfma_f32_16x16x32_bf16(al[mt], bh[nt], acc[mt][nt], 0, 0, 0);
      }
  }

  const int col_l = lane & 15;
  const int row_l = (lane >> 4) * 4;
#pragma unroll
  for (int mt = 0; mt < 4; ++mt) {
#pragma unroll
    for (int nt = 0; nt < 4; ++nt) {
      int n = (n_tile0 + nt) * 16 + col_l;
      int i = n >> 6, j = n & 63;
      float bse = base_log[n];
#pragma unroll
      for (int r = 0; r < 4; ++r) {
        int m = (m_tile0 + mt) * 16 + row_l + r;
        float v = acc[mt][nt][r] + bse;
        v = fminf(fmaxf(v, -15.0f), 3.0f);
        ushort e = (i == j) ? (ushort)0 : bf16_rne(expf(v));
        rates[(size_t)m * 4096 + n] = e;
      }
    }
  }
}

// ===== row-layout Gauss-Jordan: lane = row; pivot-row broadcast via bpermute =====
template <int K>
struct GJ {
  static __device__ __forceinline__ void run(float (&a)[64], float& d, int lane) {
    float piv = bperm(a[K], K);
    float rp = __builtin_amdgcn_rcpf(piv);
    bool isk = (lane == K);
    float m = isk ? 0.0f : a[K] * rp;
    d = isk ? piv : d;
#pragma unroll
    for (int j = K + 1; j < 64; ++j) {
      float p = bperm(a[j], K);
      a[j] = fmaf(-m, p, a[j]);
    }
    GJ<K + 1>::run(a, d, lane);
  }
};
template <>
struct GJ<63> {
  static __device__ __forceinline__ void run(float (&)[64], float&, int) {}
};

// ---- solve + attention + logits: one wave per batch (bf16 rates input) ----
__global__ __launch_bounds__(256) void solve_kernel(const ushort* __restrict__ rates,
                                                    const int* __restrict__ labels,
                                                    const float* __restrict__ Bm,
                                                    float* __restrict__ out,
                                                    int b0) {
  __shared__ float Blds[64][16];
  __shared__ float xbuf[4][64];
  __shared__ float att_lds[4][16];
  __shared__ float acc[4][80];

  const int tid = threadIdx.x;
  for (int idx = tid; idx < 1024; idx += 256)
    Blds[idx >> 4][idx & 15] = Bm[idx];

  const int wave = tid >> 6;
  const int lane = tid & 63;
  const int batch = b0 + blockIdx.x * 4 + wave;
  const ushort* Rb = rates + (size_t)(blockIdx.x * 4 + wave) * 4096;

  // ---- pass 1: cs = colsum of column `lane` (diag entries are 0) ----
  float cs = 0.0f;
#pragma unroll
  for (int i = 0; i < 64; ++i)
    cs += __uint_as_float((uint32_t)Rb[i * 64 + lane] << 16);

  // ---- pass 2: lane holds ROW `lane`: a[j] = rates[lane][j] (L1/L2 hot) ----
  const ushort* R = Rb + (size_t)lane * 64;
  float a[64];
#pragma unroll
  for (int q = 0; q < 8; ++q) {
    uint4 u = *(const uint4*)(R + q * 8);
    uint32_t ww[4] = {u.x, u.y, u.z, u.w};
#pragma unroll
    for (int t = 0; t < 4; ++t) {
      a[q * 8 + t * 2 + 0] = __uint_as_float(ww[t] << 16);
      a[q * 8 + t * 2 + 1] = __uint_as_float(ww[t] & 0xFFFF0000u);
    }
  }

  // ---- build K_mod: diag = -colsum (rows 0..62); row 63 = all ones ----
  const bool is63 = (lane == 63);
  const float ncs = -cs;
#pragma unroll
  for (int j = 0; j < 64; ++j) {
    float v = (lane == j) ? ncs : a[j];
    a[j] = is63 ? 1.0f : v;
  }

  // ---- Gauss-Jordan pivots 0..62 (no pivoting; col-diag-dominant). b=e63 untouched. ----
  float d = 1.0f;
  GJ<0>::run(a, d, lane);

  // row i<63:  d_i*x_i + a[63]*x63 = 0 ;  row 63: a[63]*x63 = 1
  float m6363 = rdlane(a[63], 63);
  float x63 = 1.0f / m6363;
  float x = is63 ? x63 : -a[63] * x63 * __builtin_amdgcn_rcpf(d);

  // clip >= 0 and normalize
  x = fmaxf(x, 0.0f);
  float s = x;
  s += __shfl_xor(s, 32); s += __shfl_xor(s, 16); s += __shfl_xor(s, 8);
  s += __shfl_xor(s, 4);  s += __shfl_xor(s, 2);  s += __shfl_xor(s, 1);
  x = x / s;

  xbuf[wave][lane] = x;
  if (lane < 16) {
    acc[wave][lane] = 1e-10f;
    acc[wave][16 + lane] = 1e-10f;
    acc[wave][32 + lane] = 1e-10f;
    acc[wave][48 + lane] = 1e-10f;
    acc[wave][64 + lane] = 1e-10f;
  }
  __syncthreads();

  // q[t] = p . B[:,t] for t = lane < 16
  float q = 0.0f;
  if (lane < 16) {
#pragma unroll 8
    for (int n = 0; n < 64; ++n) q = fmaf(xbuf[wave][n], Blds[n][lane], q);
  }
  float qm = q;
  qm = fmaxf(qm, __shfl_xor(qm, 8)); qm = fmaxf(qm, __shfl_xor(qm, 4));
  qm = fmaxf(qm, __shfl_xor(qm, 2)); qm = fmaxf(qm, __shfl_xor(qm, 1));
  float e = expf(q - qm);
  float es = e;
  es += __shfl_xor(es, 8); es += __shfl_xor(es, 4);
  es += __shfl_xor(es, 2); es += __shfl_xor(es, 1);
  if (lane < 16) att_lds[wave][lane] = e / es;
  __syncthreads();

  // deterministic serial bucket-accumulate (no atomics)
  if (lane == 0) {
#pragma unroll
    for (int n = 0; n < 16; ++n) {
      int lb = labels[(size_t)batch * 16 + n];
      acc[wave][lb - 1] += att_lds[wave][n];
    }
  }
  __syncthreads();

  float* ob = out + (size_t)batch * 75;
  ob[lane] = logf(acc[wave][lane]);
  if (lane < 11) ob[64 + lane] = logf(acc[wave][64 + lane]);
}

extern "C" void kernel_launch(void* const* d_in, const int* in_sizes, int n_in,
                              void* d_out, int out_size, void* d_ws, size_t ws_size,
                              hipStream_t stream) {
  const float* z      = (const float*)d_in[0];
  const int*   labels = (const int*)d_in[1];
  const float* Kp     = (const float*)d_in[2];
  const float* Lm     = (const float*)d_in[3];
  const float* Bm     = (const float*)d_in[4];
  const float* base   = (const float*)d_in[5];
  float* out = (float*)d_out;

  const int bsz = in_sizes[0] / ZFULL;  // 8192

  const size_t B_bytes = (size_t)256 * 5 * 2 * 64 * 8 * sizeof(ushort);  // 2.62 MB
  int CH = bsz;
  while (CH > 128) {
    size_t A_bytes = (size_t)(CH / 16) * 5 * 2 * 64 * 8 * sizeof(ushort);
    size_t need = B_bytes + A_bytes + (size_t)CH * 4096 * sizeof(ushort);
    if (need <= ws_size) break;
    CH >>= 1;
  }
  ushort* Bpk = (ushort*)d_ws;
  ushort* Apk = (ushort*)((char*)d_ws + B_bytes);
  size_t A_bytes = (size_t)(CH / 16) * 5 * 2 * 64 * 8 * sizeof(ushort);
  ushort* rates = (ushort*)((char*)d_ws + B_bytes + A_bytes);

  pack_B<<<(256 * 640 + 255) / 256, 256, 0, stream>>>(Kp, Lm, Bpk);

  for (int b0 = 0; b0 < bsz; b0 += CH) {
    int a_threads = (CH / 16) * 640;
    pack_A<<<(a_threads + 255) / 256, 256, 0, stream>>>(z, labels, Apk, b0, CH);
    dim3 g(CH / 128, 32);
    gemm_mfma<<<g, 256, 0, stream>>>(Apk, Bpk, base, rates);
    solve_kernel<<<CH / 4, 256, 0, stream>>>(rates, labels, Bm, out, b0);
  }
}

// Round 13
// 138.677 us; speedup vs baseline: 1.5766x; 1.0290x over previous
//
#include <hip/hip_runtime.h>
#include <cstdint>

#define ZFULL 136
#define NCTX 16
#define KCLS 75

typedef __bf16 bf16x8 __attribute__((ext_vector_type(8)));
typedef float f32x4 __attribute__((ext_vector_type(4)));

__device__ __forceinline__ ushort bf16_rne(float v) {
  uint32_t u = __float_as_uint(v);
  return (ushort)((u + 0x7fffu + ((u >> 16) & 1u)) >> 16);
}

__device__ __forceinline__ float rdlane(float v, int l) {
  return __int_as_float(__builtin_amdgcn_readlane(__float_as_int(v), l));
}

__device__ __forceinline__ float bperm(float v, int srcLane) {
  return __int_as_float(__builtin_amdgcn_ds_bpermute(srcLane * 4, __float_as_int(v)));
}

// packed bf16 convert: dword = (bf16(lo) | bf16(hi)<<16), RNE. No builtin on
// gfx950 -> inline asm.
__device__ __forceinline__ uint32_t cvt_pk_bf16(float lo, float hi) {
  uint32_t d;
  asm("v_cvt_pk_bf16_f32 %0, %1, %2" : "=v"(d) : "v"(lo), "v"(hi));
  return d;
}

// ---- pack A: [CH/16 m_tiles][5 k_tiles][2 h][64 lane][8 j] ushorts (bf16) ----
__global__ __launch_bounds__(256) void pack_A(const float* __restrict__ z,
                                              const int* __restrict__ labels,
                                              ushort* __restrict__ Apk,
                                              int b0, int CH) {
  int idx = blockIdx.x * 256 + threadIdx.x;  // (mt,kt,h,lane)
  int lane = idx & 63;
  int h = (idx >> 6) & 1;
  int kt = (idx >> 7) % 5;
  int mt = idx / 640;
  if (mt >= CH / 16) return;
  int m = b0 + mt * 16 + (lane & 15);
  int kbase = kt * 32 + (lane >> 4) * 8;
  ushort o[8];
#pragma unroll
  for (int j = 0; j < 8; ++j) {
    int k = kbase + j;
    float v = 0.0f;
    if (k < ZFULL) v = z[(size_t)m * ZFULL + k];
    else if (k < ZFULL + NCTX) v = (float)labels[(size_t)m * NCTX + (k - ZFULL)];
    ushort hi = bf16_rne(v);
    if (h == 0) o[j] = hi;
    else {
      float fhi = __uint_as_float((uint32_t)hi << 16);
      o[j] = bf16_rne(v - fhi);
    }
  }
  uint4 w;
  w.x = (uint32_t)o[0] | ((uint32_t)o[1] << 16);
  w.y = (uint32_t)o[2] | ((uint32_t)o[3] << 16);
  w.z = (uint32_t)o[4] | ((uint32_t)o[5] << 16);
  w.w = (uint32_t)o[6] | ((uint32_t)o[7] << 16);
  *(uint4*)(Apk + (size_t)idx * 8) = w;
}

// ---- pack B: [256 n_tiles][5 k_tiles][2 h][64 lane][8 j] ushorts (bf16) ----
__global__ __launch_bounds__(256) void pack_B(const float* __restrict__ Kp,
                                              const float* __restrict__ Lm,
                                              ushort* __restrict__ Bpk) {
  int idx = blockIdx.x * 256 + threadIdx.x;
  int lane = idx & 63;
  int h = (idx >> 6) & 1;
  int kt = (idx >> 7) % 5;
  int nt = idx / 640;
  if (nt >= 256) return;
  int n = nt * 16 + (lane & 15);
  int kbase = kt * 32 + (lane >> 4) * 8;
  ushort o[8];
#pragma unroll
  for (int j = 0; j < 8; ++j) {
    int k = kbase + j;
    float v = 0.0f;
    if (k < ZFULL) v = Kp[(size_t)n * ZFULL + k];
    else if (k < ZFULL + NCTX) v = Lm[(size_t)n * NCTX + (k - ZFULL)];
    ushort hi = bf16_rne(v);
    if (h == 0) o[j] = hi;
    else {
      float fhi = __uint_as_float((uint32_t)hi << 16);
      o[j] = bf16_rne(v - fhi);
    }
  }
  uint4 w;
  w.x = (uint32_t)o[0] | ((uint32_t)o[1] << 16);
  w.y = (uint32_t)o[2] | ((uint32_t)o[3] << 16);
  w.z = (uint32_t)o[4] | ((uint32_t)o[5] << 16);
  w.w = (uint32_t)o[6] | ((uint32_t)o[7] << 16);
  *(uint4*)(Bpk + (size_t)idx * 8) = w;
}

// ---- split-bf16 MFMA GEMM -> bf16 rates ----
// Epilogue: __expf + lane-pair exchange + v_cvt_pk_bf16_f32 + dword stores
// (r13: halves store count, ~8 ops -> 1 per bf16 pair).
__global__ __launch_bounds__(256) void gemm_mfma(const ushort* __restrict__ Apk,
                                                 const ushort* __restrict__ Bpk,
                                                 const float* __restrict__ base_log,
                                                 ushort* __restrict__ rates) {
  const int tid = threadIdx.x;
  const int lane = tid & 63;
  const int w = tid >> 6;
  const int wm = w & 1, wn = w >> 1;
  const int m_tile0 = blockIdx.x * 8 + wm * 4;
  const int n_tile0 = blockIdx.y * 8 + wn * 4;

  f32x4 acc[4][4] = {};

#pragma unroll
  for (int kt = 0; kt < 5; ++kt) {
    bf16x8 ah[4], al[4], bh[4], bl[4];
#pragma unroll
    for (int mt = 0; mt < 4; ++mt) {
      size_t off = (((size_t)(m_tile0 + mt) * 5 + kt) * 128 + lane) * 8;
      ah[mt] = *(const bf16x8*)(Apk + off);
      al[mt] = *(const bf16x8*)(Apk + off + 512);
    }
#pragma unroll
    for (int nt = 0; nt < 4; ++nt) {
      size_t off = (((size_t)(n_tile0 + nt) * 5 + kt) * 128 + lane) * 8;
      bh[nt] = *(const bf16x8*)(Bpk + off);
      bl[nt] = *(const bf16x8*)(Bpk + off + 512);
    }
#pragma unroll
    for (int mt = 0; mt < 4; ++mt)
#pragma unroll
      for (int nt = 0; nt < 4; ++nt) {
        acc[mt][nt] = __builtin_amdgcn_mfma_f32_16x16x32_bf16(ah[mt], bh[nt], acc[mt][nt], 0, 0, 0);
        acc[mt][nt] = __builtin_amdgcn_mfma_f32_16x16x32_bf16(ah[mt], bl[nt], acc[mt][nt], 0, 0, 0);
        acc[mt][nt] = __builtin_amdgcn_mfma_f32_16x16x32_bf16(al[mt], bh[nt], acc[mt][nt], 0, 0, 0);
      }
  }

  const int col_l = lane & 15;
  const int row_l = (lane >> 4) * 4;
  const bool evenc = (col_l & 1) == 0;
  const int r0 = evenc ? 0 : 2;  // even cols store rows r=0,1; odd cols r=2,3
#pragma unroll
  for (int mt = 0; mt < 4; ++mt) {
#pragma unroll
    for (int nt = 0; nt < 4; ++nt) {
      int n = (n_tile0 + nt) * 16 + col_l;
      int i = n >> 6, j = n & 63;
      float bse = base_log[n];
      float x[4];
#pragma unroll
      for (int r = 0; r < 4; ++r) {
        float v = acc[mt][nt][r] + bse;
        v = fminf(fmaxf(v, -15.0f), 3.0f);
        float e = __expf(v);
        x[r] = (i == j) ? 0.0f : e;
      }
#pragma unroll
      for (int rr = 0; rr < 2; ++rr) {
        int r = r0 + rr;
        float y = __shfl_xor(x[r], 1);  // partner holds col n^1
        float lo = evenc ? x[r] : y;
        float hi = evenc ? y : x[r];
        uint32_t dw = cvt_pk_bf16(lo, hi);
        int m = (m_tile0 + mt) * 16 + row_l + r;
        *(uint32_t*)(rates + (size_t)m * 4096 + (n & ~1)) = dw;
      }
      // the two rows this lane does NOT store still needed their x[] for the
      // partner's exchange above (shfl is symmetric) — handled: shfl_xor on
      // x[r] for r=r0..r0+1 reads the partner's same-r values.
      // Rows r0^2..r0^2+1 are stored by the partner lane.
#pragma unroll
      for (int rr = 0; rr < 2; ++rr) {
        int r = (r0 ^ 2) + rr;
        // partner needs our x[r] via its shfl; issue matching shfl to keep
        // the exchange collective and uniform.
        float y = __shfl_xor(x[r], 1);
        (void)y;
      }
    }
  }
}

// ===== row-layout Gauss-Jordan: lane = row; pivot-row broadcast via bpermute =====
template <int K>
struct GJ {
  static __device__ __forceinline__ void run(float (&a)[64], float& d, int lane) {
    float piv = bperm(a[K], K);
    float rp = __builtin_amdgcn_rcpf(piv);
    bool isk = (lane == K);
    float m = isk ? 0.0f : a[K] * rp;
    d = isk ? piv : d;
#pragma unroll
    for (int j = K + 1; j < 64; ++j) {
      float p = bperm(a[j], K);
      a[j] = fmaf(-m, p, a[j]);
    }
    GJ<K + 1>::run(a, d, lane);
  }
};
template <>
struct GJ<63> {
  static __device__ __forceinline__ void run(float (&)[64], float&, int) {}
};

// ---- solve + attention + logits: one wave per batch (bf16 rates input) ----
__global__ __launch_bounds__(256) void solve_kernel(const ushort* __restrict__ rates,
                                                    const int* __restrict__ labels,
                                                    const float* __restrict__ Bm,
                                                    float* __restrict__ out,
                                                    int b0) {
  __shared__ float Blds[64][16];
  __shared__ float xbuf[4][64];
  __shared__ float att_lds[4][16];
  __shared__ float acc[4][80];

  const int tid = threadIdx.x;
  for (int idx = tid; idx < 1024; idx += 256)
    Blds[idx >> 4][idx & 15] = Bm[idx];

  const int wave = tid >> 6;
  const int lane = tid & 63;
  const int batch = b0 + blockIdx.x * 4 + wave;
  const ushort* Rb = rates + (size_t)(blockIdx.x * 4 + wave) * 4096;

  // ---- pass 1: cs = colsum of column `lane` (diag entries are 0) ----
  float cs = 0.0f;
#pragma unroll
  for (int i = 0; i < 64; ++i)
    cs += __uint_as_float((uint32_t)Rb[i * 64 + lane] << 16);

  // ---- pass 2: lane holds ROW `lane`: a[j] = rates[lane][j] (L1/L2 hot) ----
  const ushort* R = Rb + (size_t)lane * 64;
  float a[64];
#pragma unroll
  for (int q = 0; q < 8; ++q) {
    uint4 u = *(const uint4*)(R + q * 8);
    uint32_t ww[4] = {u.x, u.y, u.z, u.w};
#pragma unroll
    for (int t = 0; t < 4; ++t) {
      a[q * 8 + t * 2 + 0] = __uint_as_float(ww[t] << 16);
      a[q * 8 + t * 2 + 1] = __uint_as_float(ww[t] & 0xFFFF0000u);
    }
  }

  // ---- build K_mod: diag = -colsum (rows 0..62); row 63 = all ones ----
  const bool is63 = (lane == 63);
  const float ncs = -cs;
#pragma unroll
  for (int j = 0; j < 64; ++j) {
    float v = (lane == j) ? ncs : a[j];
    a[j] = is63 ? 1.0f : v;
  }

  // ---- Gauss-Jordan pivots 0..62 (no pivoting; col-diag-dominant). b=e63 untouched. ----
  float d = 1.0f;
  GJ<0>::run(a, d, lane);

  // row i<63:  d_i*x_i + a[63]*x63 = 0 ;  row 63: a[63]*x63 = 1
  float m6363 = rdlane(a[63], 63);
  float x63 = 1.0f / m6363;
  float x = is63 ? x63 : -a[63] * x63 * __builtin_amdgcn_rcpf(d);

  // clip >= 0 and normalize
  x = fmaxf(x, 0.0f);
  float s = x;
  s += __shfl_xor(s, 32); s += __shfl_xor(s, 16); s += __shfl_xor(s, 8);
  s += __shfl_xor(s, 4);  s += __shfl_xor(s, 2);  s += __shfl_xor(s, 1);
  x = x / s;

  xbuf[wave][lane] = x;
  if (lane < 16) {
    acc[wave][lane] = 1e-10f;
    acc[wave][16 + lane] = 1e-10f;
    acc[wave][32 + lane] = 1e-10f;
    acc[wave][48 + lane] = 1e-10f;
    acc[wave][64 + lane] = 1e-10f;
  }
  __syncthreads();

  // q[t] = p . B[:,t] for t = lane < 16
  float q = 0.0f;
  if (lane < 16) {
#pragma unroll 8
    for (int n = 0; n < 64; ++n) q = fmaf(xbuf[wave][n], Blds[n][lane], q);
  }
  float qm = q;
  qm = fmaxf(qm, __shfl_xor(qm, 8)); qm = fmaxf(qm, __shfl_xor(qm, 4));
  qm = fmaxf(qm, __shfl_xor(qm, 2)); qm = fmaxf(qm, __shfl_xor(qm, 1));
  float e = expf(q - qm);
  float es = e;
  es += __shfl_xor(es, 8); es += __shfl_xor(es, 4);
  es += __shfl_xor(es, 2); es += __shfl_xor(es, 1);
  if (lane < 16) att_lds[wave][lane] = e / es;
  __syncthreads();

  // deterministic serial bucket-accumulate (no atomics)
  if (lane == 0) {
#pragma unroll
    for (int n = 0; n < 16; ++n) {
      int lb = labels[(size_t)batch * 16 + n];
      acc[wave][lb - 1] += att_lds[wave][n];
    }
  }
  __syncthreads();

  float* ob = out + (size_t)batch * 75;
  ob[lane] = logf(acc[wave][lane]);
  if (lane < 11) ob[64 + lane] = logf(acc[wave][64 + lane]);
}

extern "C" void kernel_launch(void* const* d_in, const int* in_sizes, int n_in,
                              void* d_out, int out_size, void* d_ws, size_t ws_size,
                              hipStream_t stream) {
  const float* z      = (const float*)d_in[0];
  const int*   labels = (const int*)d_in[1];
  const float* Kp     = (const float*)d_in[2];
  const float* Lm     = (const float*)d_in[3];
  const float* Bm     = (const float*)d_in[4];
  const float* base   = (const float*)d_in[5];
  float* out = (float*)d_out;

  const int bsz = in_sizes[0] / ZFULL;  // 8192

  const size_t B_bytes = (size_t)256 * 5 * 2 * 64 * 8 * sizeof(ushort);  // 2.62 MB
  int CH = bsz;
  while (CH > 128) {
    size_t A_bytes = (size_t)(CH / 16) * 5 * 2 * 64 * 8 * sizeof(ushort);
    size_t need = B_bytes + A_bytes + (size_t)CH * 4096 * sizeof(ushort);
    if (need <= ws_size) break;
    CH >>= 1;
  }
  ushort* Bpk = (ushort*)d_ws;
  ushort* Apk = (ushort*)((char*)d_ws + B_bytes);
  size_t A_bytes = (size_t)(CH / 16) * 5 * 2 * 64 * 8 * sizeof(ushort);
  ushort* rates = (ushort*)((char*)d_ws + B_bytes + A_bytes);

  pack_B<<<(256 * 640 + 255) / 256, 256, 0, stream>>>(Kp, Lm, Bpk);

  for (int b0 = 0; b0 < bsz; b0 += CH) {
    int a_threads = (CH / 16) * 640;
    pack_A<<<(a_threads + 255) / 256, 256, 0, stream>>>(z, labels, Apk, b0, CH);
    dim3 g(CH / 128, 32);
    gemm_mfma<<<g, 256, 0, stream>>>(Apk, Bpk, base, rates);
    solve_kernel<<<CH / 4, 256, 0, stream>>>(rates, labels, Bm, out, b0);
  }
}